// Round 7
// baseline (183.645 us; speedup 1.0000x reference)
//
#include <hip/hip_runtime.h>
#include <hip/hip_bf16.h>
#include <math.h>

typedef __attribute__((ext_vector_type(8))) short bf16x8;
typedef __attribute__((ext_vector_type(4))) float f32x4;

__device__ __forceinline__ float leaky(float x) { return x > 0.0f ? x : 0.01f * x; }

__device__ __forceinline__ unsigned short f2b(float f) {
    unsigned u = __builtin_bit_cast(unsigned, f);
    u += 0x7fffu + ((u >> 16) & 1u);
    return (unsigned short)(u >> 16);
}

__device__ __forceinline__ bf16x8 cvt8(float4 u0, float4 u1) {
    bf16x8 r;
    r[0] = (short)f2b(u0.x); r[1] = (short)f2b(u0.y);
    r[2] = (short)f2b(u0.z); r[3] = (short)f2b(u0.w);
    r[4] = (short)f2b(u1.x); r[5] = (short)f2b(u1.y);
    r[6] = (short)f2b(u1.z); r[7] = (short)f2b(u1.w);
    return r;
}

// ---------- dispatch 1: both HW means -> bf16 ; blocks >= 32768 zero C bufs + counters ----------
__global__ __launch_bounds__(256) void means_kernel(const float* __restrict__ xm,
                                                    const float* __restrict__ xd,
                                                    unsigned short* __restrict__ xm_b,
                                                    unsigned short* __restrict__ xd_b,
                                                    float4* __restrict__ zbase)
{
    int blk = blockIdx.x;
    int tid = threadIdx.x;
    if (blk >= 32768) {                            // zero 2.5 MB C buffers + counter page
        int idx = (blk - 32768) * 256 + tid;       // 641 blocks -> floats [0, 656384)
        zbase[idx] = make_float4(0.f, 0.f, 0.f, 0.f);
        return;
    }
    if (blk < 16384) {
        int lane = tid & 63;
        int wid  = tid >> 6;
        int row  = blk * 4 + wid;                  // 0..65535
        const float4* r = (const float4*)(xm + (size_t)row * 784);
        float s = 0.0f;
        for (int i = lane; i < 196; i += 64) {
            float4 v = r[i];
            s += v.x + v.y + v.z + v.w;
        }
        #pragma unroll
        for (int off = 32; off; off >>= 1) s += __shfl_xor(s, off);
        if (lane == 0) xm_b[row] = f2b(s * (1.0f / 784.0f));
    } else {
        int b2  = blk - 16384;
        int sub = tid & 15;
        int r   = tid >> 4;
        int row = b2 * 16 + r;                     // 0..262143
        const float* base = xd + (size_t)row * 49;
        float s = base[sub] + base[sub + 16] + base[sub + 32];
        if (sub == 0) s += base[48];
        #pragma unroll
        for (int off = 8; off; off >>= 1) s += __shfl_xor(s, off);
        if (sub == 0) xd_b[row] = f2b(s * (1.0f / 49.0f));
    }
}

// ---------- gate: block-wide wait until *cnt >= target (LLC acquire poll) ----------
__device__ __forceinline__ void gate(int* cnt, int target) {
    if (threadIdx.x == 0) {
        while (__hip_atomic_load(cnt, __ATOMIC_ACQUIRE, __HIP_MEMORY_SCOPE_AGENT) < target)
            __builtin_amdgcn_s_sleep(8);
    }
    __syncthreads();
}

// ---------- GEMM phase: C[m][n] += actA(A[m][k-slice]) @ B[n][k-slice]^T ----------
// block 512 thr = 8 waves; wave w rows 16w..16w+15, cols n0..n0+31; LDS-staged bf16 B.
// A lane layout: row=l&15, kchunk=(l>>4)*8 ; C/D: col=l&15, row=(l>>4)*4+reg (validated R3/R6)
__device__ __forceinline__ void gemm_phase(
    const void* __restrict__ A, int af, int aact,
    const float* __restrict__ B, float* __restrict__ C,
    int N, int K, int Kc, int k0, int n0,
    unsigned short (*Bs)[72], int tid)
{
    const int l  = tid & 63;
    const int lr = l & 15;
    const int lc = l >> 4;
    const int m0 = (tid >> 6) * 16;
    const int srow = tid >> 4;                     // 0..31
    const int scol = (tid & 15) * 4;               // 0,4,..,60

    f32x4 acc0 = {0.f,0.f,0.f,0.f}, acc1 = {0.f,0.f,0.f,0.f};

    for (int kt = 0; kt < Kc; kt += 64) {
        float4 v = *(const float4*)(B + (size_t)(n0 + srow) * K + k0 + kt + scol);
        __syncthreads();                           // prev-iter Bs reads done
        Bs[srow][scol + 0] = f2b(v.x);
        Bs[srow][scol + 1] = f2b(v.y);
        Bs[srow][scol + 2] = f2b(v.z);
        Bs[srow][scol + 3] = f2b(v.w);
        __syncthreads();

        #pragma unroll
        for (int kc = 0; kc < 2; ++kc) {
            size_t aoff = (size_t)(m0 + lr) * K + k0 + kt + kc * 32 + lc * 8;
            bf16x8 a;
            if (!af) {
                a = *(const bf16x8*)((const unsigned short*)A + aoff);
            } else {
                const float* p = (const float*)A + aoff;
                float4 u0 = *(const float4*)p;
                float4 u1 = *(const float4*)(p + 4);
                if (aact) {
                    u0.x = leaky(u0.x); u0.y = leaky(u0.y);
                    u0.z = leaky(u0.z); u0.w = leaky(u0.w);
                    u1.x = leaky(u1.x); u1.y = leaky(u1.y);
                    u1.z = leaky(u1.z); u1.w = leaky(u1.w);
                }
                a = cvt8(u0, u1);
            }
            bf16x8 b0 = *(const bf16x8*)&Bs[lr][kc * 32 + lc * 8];
            bf16x8 b1 = *(const bf16x8*)&Bs[16 + lr][kc * 32 + lc * 8];
            acc0 = __builtin_amdgcn_mfma_f32_16x16x32_bf16(a, b0, acc0, 0, 0, 0);
            acc1 = __builtin_amdgcn_mfma_f32_16x16x32_bf16(a, b1, acc1, 0, 0, 0);
        }
    }

    #pragma unroll
    for (int r = 0; r < 4; ++r) {
        int m = m0 + lc * 4 + r;
        atomicAdd(&C[(size_t)m * N + n0 + lr],      acc0[r]);
        atomicAdd(&C[(size_t)m * N + n0 + 16 + lr], acc1[r]);
    }
}

// ---------- dispatch 2: fused G1+G2+G3+tail+finalize with counter gates ----------
// bid 0..255:    G1  shallow_in C1 = xm_b @ w_shallow^T           (N=2048,K=512, S=4)
// bid 256..767:  G2  z0: C2o = xd_b @ ow1^T ; z1(gated): C2s = C1 @ sw1^T (N=1024,K=2048,S=8)
// bid 768..1023: G3  (gated) C3{o,s} = leaky(C2{o,s}) @ {ow2,sw2}^T (N=512,K=1024,S=8)
// bid 1024..1151: tail per-sample (gated); last block finalizes.
__global__ __launch_bounds__(512, 4) void fused_kernel(
    float* __restrict__ wf,
    const unsigned short* __restrict__ xm_b, const unsigned short* __restrict__ xd_b,
    const float* __restrict__ w_shallow,
    const float* __restrict__ ow1, const float* __restrict__ ow2, const float* __restrict__ ow3,
    const float* __restrict__ sw1, const float* __restrict__ sw2, const float* __restrict__ sw3,
    const float* __restrict__ tw1, const float* __restrict__ tw2,
    const float* __restrict__ cw1, const float* __restrict__ cw2,
    const float* __restrict__ qw1, const float* __restrict__ qw2,
    const float* __restrict__ center, const float* __restrict__ proto,
    float* __restrict__ out)
{
    __shared__ unsigned short Bs[32][72];
    __shared__ float o2r[512], s2r[512];
    __shared__ float red[2][64][4];
    __shared__ float o3s[64], s3s[64], t1s[64], c1s[64], q1s[64];
    __shared__ float tmp[4][8];
    __shared__ int flag;

    float* C1  = wf;                    // [128,2048]
    float* C2o = wf + 262144;           // [128,1024]
    float* C2s = wf + 393216;           // [128,1024]
    float* C3o = wf + 524288;           // [128,512]
    float* C3s = wf + 589824;           // [128,512]
    int*   cnt = (int*)(wf + 655360);   // [4] zeroed by dispatch 1
    float* ce_t = wf + 655616;          // [128] x4, atomic-written
    float* osv  = ce_t + 128;
    float* csv  = ce_t + 256;
    float* alv  = ce_t + 384;

    const int bid = blockIdx.x;
    const int tid = threadIdx.x;

    if (bid < 256) {
        int nt = bid >> 2, s = bid & 3;
        gemm_phase(xm_b, 0, 0, w_shallow, C1, 2048, 512, 128, s * 128, nt * 32, Bs, tid);
        __syncthreads();
        if (tid == 0) __hip_atomic_fetch_add(&cnt[0], 1, __ATOMIC_RELEASE, __HIP_MEMORY_SCOPE_AGENT);
        return;
    }
    if (bid < 768) {
        int b2 = bid - 256;
        int z = b2 >> 8, idx = b2 & 255, nt = idx >> 3, s = idx & 7;
        if (z == 0) {
            gemm_phase(xd_b, 0, 0, ow1, C2o, 1024, 2048, 256, s * 256, nt * 32, Bs, tid);
        } else {
            gate(&cnt[0], 256);
            gemm_phase(C1, 1, 0, sw1, C2s, 1024, 2048, 256, s * 256, nt * 32, Bs, tid);
        }
        __syncthreads();
        if (tid == 0) __hip_atomic_fetch_add(&cnt[1], 1, __ATOMIC_RELEASE, __HIP_MEMORY_SCOPE_AGENT);
        return;
    }
    if (bid < 1024) {
        int b3 = bid - 768;
        int z = b3 >> 7, idx = b3 & 127, nt = idx >> 3, s = idx & 7;
        gate(&cnt[1], 512);
        gemm_phase(z ? C2s : C2o, 1, 1, z ? sw2 : ow2, z ? C3s : C3o,
                   512, 1024, 128, s * 128, nt * 32, Bs, tid);
        __syncthreads();
        if (tid == 0) __hip_atomic_fetch_add(&cnt[2], 1, __ATOMIC_RELEASE, __HIP_MEMORY_SCOPE_AGENT);
        return;
    }

    // ---------------- tail ----------------
    const int b = bid - 1024;
    gate(&cnt[2], 256);

    {   // layer-2 activation
        int e = tid;
        o2r[e] = leaky(C3o[b * 512 + e]);
        s2r[e] = leaky(C3s[b * 512 + e]);
    }
    __syncthreads();
    {   // both layer-3 matvecs: p=path, o=output, q=K-quarter
        int p = tid >> 8, o = (tid >> 2) & 63, q = tid & 3;
        const float* wr = (p ? sw3 : ow3) + (size_t)o * 512 + q * 128;
        const float* xr = (p ? s2r : o2r) + q * 128;
        float acc = 0.f;
        for (int j = 0; j < 128; ++j) acc += wr[j] * xr[j];
        red[p][o][q] = acc;
    }
    __syncthreads();
    if (tid < 128) {
        int p = tid >> 6, o = tid & 63;
        float v = leaky(red[p][o][0] + red[p][o][1] + red[p][o][2] + red[p][o][3]);
        if (p) s3s[o] = v; else o3s[o] = v;
    }
    __syncthreads();

    float ce_val = 0.f;
    int o = tid;
    if (tid < 64) {
        float acc = 0.f;
        for (int j = 0; j < 64; ++j) acc += tw1[o * 128 + j] * s3s[j];
        for (int j = 0; j < 64; ++j) acc += tw1[o * 128 + 64 + j] * (s3s[j] - center[j]);
        t1s[o] = leaky(acc);
    }
    __syncthreads();
    if (tid < 64) {
        float acc = 0.f;
        for (int j = 0; j < 64; ++j) acc += tw2[o * 64 + j] * t1s[j];
        float tex = leaky(acc);
        float sim[4];
        #pragma unroll
        for (int k = 0; k < 4; ++k) {
            float d = tex - proto[k * 64 + o];
            float v = d * d;
            #pragma unroll
            for (int off = 32; off; off >>= 1) v += __shfl_xor(v, off);
            sim[k] = v;
        }
        int cat = 0; float best = sim[0];
        #pragma unroll
        for (int k = 1; k < 4; ++k) if (sim[k] > best) { best = sim[k]; cat = k; }
        float sume = 0.f;
        #pragma unroll
        for (int k = 0; k < 4; ++k) sume += expf(sim[k] - best);
        ce_val = logf(sume);
        float acc2 = 0.f;
        for (int j = 0; j < 64; ++j) acc2 += cw1[o * 128 + j] * o3s[j];
        for (int j = 0; j < 64; ++j) acc2 += cw1[o * 128 + 64 + j] * (o3s[j] - proto[cat * 64 + j]);
        c1s[o] = leaky(acc2);
        acc2 = 0.f;
        for (int j = 0; j < 64; ++j) acc2 += qw1[o * 64 + j] * o3s[j];
        q1s[o] = leaky(acc2);
    }
    __syncthreads();
    if (tid < 64) {
        float acc = 0.f;
        for (int j = 0; j < 64; ++j) acc += cw2[o * 64 + j] * c1s[j];
        float cf = leaky(acc);
        float dc = cf - center[o];
        float cs = dc * dc;
        #pragma unroll
        for (int off = 32; off; off >>= 1) cs += __shfl_xor(cs, off);
        acc = 0.f;
        for (int j = 0; j < 64; ++j) acc += qw2[o * 64 + j] * q1s[j];
        float qf = leaky(acc);
        float dq = qf - center[o];
        float os = dq * dq;
        #pragma unroll
        for (int off = 32; off; off >>= 1) os += __shfl_xor(os, off);
        if (o == 0) {
            __hip_atomic_store(&ce_t[b], ce_val, __ATOMIC_RELAXED, __HIP_MEMORY_SCOPE_AGENT);
            __hip_atomic_store(&osv[b],  os,     __ATOMIC_RELAXED, __HIP_MEMORY_SCOPE_AGENT);
            __hip_atomic_store(&csv[b],  cs,     __ATOMIC_RELAXED, __HIP_MEMORY_SCOPE_AGENT);
            __hip_atomic_store(&alv[b],  fabsf(os - cs), __ATOMIC_RELAXED, __HIP_MEMORY_SCOPE_AGENT);
        }
    }
    __syncthreads();
    if (tid == 0) {
        int old = __hip_atomic_fetch_add(&cnt[3], 1, __ATOMIC_ACQ_REL, __HIP_MEMORY_SCOPE_AGENT);
        flag = (old == 127);
    }
    __syncthreads();
    if (flag) {
        float v0 = 0.f, v1 = 0.f, v2 = 0.f, v3 = 0.f;
        if (tid < 128) {
            v0 = __hip_atomic_load(&ce_t[tid], __ATOMIC_RELAXED, __HIP_MEMORY_SCOPE_AGENT);
            v1 = __hip_atomic_load(&osv[tid],  __ATOMIC_RELAXED, __HIP_MEMORY_SCOPE_AGENT);
            v2 = __hip_atomic_load(&csv[tid],  __ATOMIC_RELAXED, __HIP_MEMORY_SCOPE_AGENT);
            v3 = __hip_atomic_load(&alv[tid],  __ATOMIC_RELAXED, __HIP_MEMORY_SCOPE_AGENT);
        }
        float v[4] = { v0, v1, v2, v3 };
        int lane = tid & 63, wv = tid >> 6;
        #pragma unroll
        for (int i = 0; i < 4; ++i) {
            float x = v[i];
            #pragma unroll
            for (int off = 32; off; off >>= 1) x += __shfl_xor(x, off);
            if (lane == 0) tmp[i][wv] = x;
        }
        __syncthreads();
        if (tid < 4) {
            float s = 0.f;
            #pragma unroll
            for (int j = 0; j < 8; ++j) s += tmp[tid][j];
            out[tid] = s * (1.0f / 128.0f);
        }
    }
}

// ---------- launcher ----------
extern "C" void kernel_launch(void* const* d_in, const int* in_sizes, int n_in,
                              void* d_out, int out_size, void* d_ws, size_t ws_size,
                              hipStream_t stream)
{
    const float* x_mid     = (const float*)d_in[0];
    const float* x_deep    = (const float*)d_in[1];
    const float* w_shallow = (const float*)d_in[2];
    const float* ow1 = (const float*)d_in[3];
    const float* ow2 = (const float*)d_in[4];
    const float* ow3 = (const float*)d_in[5];
    const float* sw1 = (const float*)d_in[6];
    const float* sw2 = (const float*)d_in[7];
    const float* sw3 = (const float*)d_in[8];
    const float* tw1 = (const float*)d_in[9];
    const float* tw2 = (const float*)d_in[10];
    const float* cw1 = (const float*)d_in[11];
    const float* cw2 = (const float*)d_in[12];
    const float* qw1 = (const float*)d_in[13];
    const float* qw2 = (const float*)d_in[14];
    const float* center = (const float*)d_in[15];
    const float* proto  = (const float*)d_in[16];
    float* out = (float*)d_out;

    float* wf = (float*)d_ws;
    // zeroed region: C1(262144) C2o(131072) C2s(131072) C3o(65536) C3s(65536) cnt/pad(1024)
    unsigned short* xm_b = (unsigned short*)(wf + 656384);            // [128,512]
    unsigned short* xd_b = (unsigned short*)((char*)xm_b + 131072);   // [128,2048]

    // dispatch 1: means + zero C bufs/counters (641 zero blocks)
    means_kernel<<<33409, 256, 0, stream>>>(x_mid, x_deep, xm_b, xd_b, (float4*)wf);

    // dispatch 2: everything else
    fused_kernel<<<1152, 512, 0, stream>>>(wf, xm_b, xd_b, w_shallow,
                                           ow1, ow2, ow3, sw1, sw2, sw3,
                                           tw1, tw2, cw1, cw2, qw1, qw2,
                                           center, proto, out);
}

// Round 8
// 132.982 us; speedup vs baseline: 1.3810x; 1.3810x over previous
//
#include <hip/hip_runtime.h>
#include <hip/hip_bf16.h>
#include <math.h>

typedef __attribute__((ext_vector_type(8))) short bf16x8;
typedef __attribute__((ext_vector_type(4))) float f32x4;

__device__ __forceinline__ float leaky(float x) { return x > 0.0f ? x : 0.01f * x; }

__device__ __forceinline__ unsigned short f2b(float f) {
    unsigned u = __builtin_bit_cast(unsigned, f);
    u += 0x7fffu + ((u >> 16) & 1u);
    return (unsigned short)(u >> 16);
}

__device__ __forceinline__ bf16x8 cvt8(float4 u0, float4 u1) {
    bf16x8 r;
    r[0] = (short)f2b(u0.x); r[1] = (short)f2b(u0.y);
    r[2] = (short)f2b(u0.z); r[3] = (short)f2b(u0.w);
    r[4] = (short)f2b(u1.x); r[5] = (short)f2b(u1.y);
    r[6] = (short)f2b(u1.z); r[7] = (short)f2b(u1.w);
    return r;
}

// ---------- dispatch 1: both HW means -> bf16 ; blocks >= 32768 zero C bufs + counters ----------
__global__ __launch_bounds__(256) void means_kernel(const float* __restrict__ xm,
                                                    const float* __restrict__ xd,
                                                    unsigned short* __restrict__ xm_b,
                                                    unsigned short* __restrict__ xd_b,
                                                    float4* __restrict__ zbase)
{
    int blk = blockIdx.x;
    int tid = threadIdx.x;
    if (blk >= 32768) {                            // zero C buffers + counter page (2.63 MB)
        int idx = (blk - 32768) * 256 + tid;       // 641 blocks -> floats [0, 656384)
        zbase[idx] = make_float4(0.f, 0.f, 0.f, 0.f);
        return;
    }
    if (blk < 16384) {
        int lane = tid & 63;
        int wid  = tid >> 6;
        int row  = blk * 4 + wid;                  // 0..65535
        const float4* r = (const float4*)(xm + (size_t)row * 784);
        float s = 0.0f;
        for (int i = lane; i < 196; i += 64) {
            float4 v = r[i];
            s += v.x + v.y + v.z + v.w;
        }
        #pragma unroll
        for (int off = 32; off; off >>= 1) s += __shfl_xor(s, off);
        if (lane == 0) xm_b[row] = f2b(s * (1.0f / 784.0f));
    } else {
        int b2  = blk - 16384;
        int sub = tid & 15;
        int r   = tid >> 4;
        int row = b2 * 16 + r;                     // 0..262143
        const float* base = xd + (size_t)row * 49;
        float s = base[sub] + base[sub + 16] + base[sub + 32];
        if (sub == 0) s += base[48];
        #pragma unroll
        for (int off = 8; off; off >>= 1) s += __shfl_xor(s, off);
        if (sub == 0) xd_b[row] = f2b(s * (1.0f / 49.0f));
    }
}

// ---------- cache-op-free gate: RELAXED poll (sc1 LLC load), ONE acquire fence at exit ----------
__device__ __forceinline__ void gate(int* cnt, int target) {
    if (threadIdx.x == 0) {
        while (__hip_atomic_load(cnt, __ATOMIC_RELAXED, __HIP_MEMORY_SCOPE_AGENT) < target)
            __builtin_amdgcn_s_sleep(4);
        __builtin_amdgcn_fence(__ATOMIC_ACQUIRE, "agent");   // single L1/L2 inv per block
    }
    __syncthreads();
}

// ---------- producer completion: drain atomics, then RELAXED count bump (no writeback) ----------
__device__ __forceinline__ void done(int* cnt) {
    __syncthreads();                               // compiler emits vmcnt(0) drain before barrier
    if (threadIdx.x == 0) {
        asm volatile("s_waitcnt vmcnt(0)" ::: "memory");
        __hip_atomic_fetch_add(cnt, 1, __ATOMIC_RELAXED, __HIP_MEMORY_SCOPE_AGENT);
    }
}

// ---------- GEMM phase: C[m][n] += actA(A[m][k-slice]) @ B[n][k-slice]^T (atomic C) ----------
// block 512 thr = 8 waves; wave w rows 16w..16w+15, cols n0..n0+31; LDS-staged bf16 B.
// A lane layout: row=l&15, kchunk=(l>>4)*8 ; C/D: col=l&15, row=(l>>4)*4+reg (validated R3/R6)
__device__ __forceinline__ void gemm_phase(
    const void* __restrict__ A, int af, int aact,
    const float* __restrict__ B, float* __restrict__ C,
    int N, int K, int Kc, int k0, int n0,
    unsigned short (*Bs)[72], int tid)
{
    const int l  = tid & 63;
    const int lr = l & 15;
    const int lc = l >> 4;
    const int m0 = (tid >> 6) * 16;
    const int srow = tid >> 4;                     // 0..31
    const int scol = (tid & 15) * 4;               // 0,4,..,60

    f32x4 acc0 = {0.f,0.f,0.f,0.f}, acc1 = {0.f,0.f,0.f,0.f};

    for (int kt = 0; kt < Kc; kt += 64) {
        float4 v = *(const float4*)(B + (size_t)(n0 + srow) * K + k0 + kt + scol);
        __syncthreads();                           // prev-iter Bs reads done
        Bs[srow][scol + 0] = f2b(v.x);
        Bs[srow][scol + 1] = f2b(v.y);
        Bs[srow][scol + 2] = f2b(v.z);
        Bs[srow][scol + 3] = f2b(v.w);
        __syncthreads();

        #pragma unroll
        for (int kc = 0; kc < 2; ++kc) {
            size_t aoff = (size_t)(m0 + lr) * K + k0 + kt + kc * 32 + lc * 8;
            bf16x8 a;
            if (!af) {
                a = *(const bf16x8*)((const unsigned short*)A + aoff);
            } else {
                const float* p = (const float*)A + aoff;
                float4 u0 = *(const float4*)p;
                float4 u1 = *(const float4*)(p + 4);
                if (aact) {
                    u0.x = leaky(u0.x); u0.y = leaky(u0.y);
                    u0.z = leaky(u0.z); u0.w = leaky(u0.w);
                    u1.x = leaky(u1.x); u1.y = leaky(u1.y);
                    u1.z = leaky(u1.z); u1.w = leaky(u1.w);
                }
                a = cvt8(u0, u1);
            }
            bf16x8 b0 = *(const bf16x8*)&Bs[lr][kc * 32 + lc * 8];
            bf16x8 b1 = *(const bf16x8*)&Bs[16 + lr][kc * 32 + lc * 8];
            acc0 = __builtin_amdgcn_mfma_f32_16x16x32_bf16(a, b0, acc0, 0, 0, 0);
            acc1 = __builtin_amdgcn_mfma_f32_16x16x32_bf16(a, b1, acc1, 0, 0, 0);
        }
    }

    #pragma unroll
    for (int r = 0; r < 4; ++r) {
        int m = m0 + lc * 4 + r;
        atomicAdd(&C[(size_t)m * N + n0 + lr],      acc0[r]);
        atomicAdd(&C[(size_t)m * N + n0 + 16 + lr], acc1[r]);
    }
}

// ---------- dispatch 2: fused G1+G2+G3+tail+finalize with relaxed-spin gates ----------
// bid 0..255:    G1  C1 = xm_b @ w_shallow^T                      (N=2048,K=512, S=4)
// bid 256..767:  G2  z0: C2o = xd_b @ ow1^T ; z1(gated): C2s = C1 @ sw1^T (N=1024,K=2048,S=8)
// bid 768..1023: G3  (gated) C3{o,s} = leaky(C2{o,s}) @ {ow2,sw2}^T (N=512,K=1024,S=8)
// bid 1024..1151: tail per-sample (gated); last-arriving tail block finalizes.
__global__ __launch_bounds__(512, 4) void fused_kernel(
    float* __restrict__ wf,
    const unsigned short* __restrict__ xm_b, const unsigned short* __restrict__ xd_b,
    const float* __restrict__ w_shallow,
    const float* __restrict__ ow1, const float* __restrict__ ow2, const float* __restrict__ ow3,
    const float* __restrict__ sw1, const float* __restrict__ sw2, const float* __restrict__ sw3,
    const float* __restrict__ tw1, const float* __restrict__ tw2,
    const float* __restrict__ cw1, const float* __restrict__ cw2,
    const float* __restrict__ qw1, const float* __restrict__ qw2,
    const float* __restrict__ center, const float* __restrict__ proto,
    float* __restrict__ out)
{
    __shared__ unsigned short Bs[32][72];
    __shared__ float o2r[512], s2r[512];
    __shared__ float red[2][64][4];
    __shared__ float o3s[64], s3s[64], t1s[64], c1s[64], q1s[64];
    __shared__ float tmp[4][8];
    __shared__ int flag;

    float* C1  = wf;                    // [128,2048]
    float* C2o = wf + 262144;           // [128,1024]
    float* C2s = wf + 393216;           // [128,1024]
    float* C3o = wf + 524288;           // [128,512]
    float* C3s = wf + 589824;           // [128,512]
    int*   cnt = (int*)(wf + 655360);   // [4], zeroed by dispatch 1
    float* ce_t = wf + 655616;          // [128] x4
    float* osv  = ce_t + 128;
    float* csv  = ce_t + 256;
    float* alv  = ce_t + 384;

    const int bid = blockIdx.x;
    const int tid = threadIdx.x;

    if (bid < 256) {
        int nt = bid >> 2, s = bid & 3;
        gemm_phase(xm_b, 0, 0, w_shallow, C1, 2048, 512, 128, s * 128, nt * 32, Bs, tid);
        done(&cnt[0]);
        return;
    }
    if (bid < 768) {
        int b2 = bid - 256;
        int z = b2 >> 8, idx = b2 & 255, nt = idx >> 3, s = idx & 7;
        if (z == 0) {
            gemm_phase(xd_b, 0, 0, ow1, C2o, 1024, 2048, 256, s * 256, nt * 32, Bs, tid);
        } else {
            gate(&cnt[0], 256);
            gemm_phase(C1, 1, 0, sw1, C2s, 1024, 2048, 256, s * 256, nt * 32, Bs, tid);
        }
        done(&cnt[1]);
        return;
    }
    if (bid < 1024) {
        int b3 = bid - 768;
        int z = b3 >> 7, idx = b3 & 127, nt = idx >> 3, s = idx & 7;
        gate(&cnt[1], 512);
        gemm_phase(z ? C2s : C2o, 1, 1, z ? sw2 : ow2, z ? C3s : C3o,
                   512, 1024, 128, s * 128, nt * 32, Bs, tid);
        done(&cnt[2]);
        return;
    }

    // ---------------- tail ----------------
    const int b = bid - 1024;
    gate(&cnt[2], 256);

    {   // layer-2 activation
        int e = tid;
        o2r[e] = leaky(C3o[b * 512 + e]);
        s2r[e] = leaky(C3s[b * 512 + e]);
    }
    __syncthreads();
    {   // both layer-3 matvecs: p=path, o=output, q=K-quarter
        int p = tid >> 8, o = (tid >> 2) & 63, q = tid & 3;
        const float* wr = (p ? sw3 : ow3) + (size_t)o * 512 + q * 128;
        const float* xr = (p ? s2r : o2r) + q * 128;
        float acc = 0.f;
        for (int j = 0; j < 128; ++j) acc += wr[j] * xr[j];
        red[p][o][q] = acc;
    }
    __syncthreads();
    if (tid < 128) {
        int p = tid >> 6, o = tid & 63;
        float v = leaky(red[p][o][0] + red[p][o][1] + red[p][o][2] + red[p][o][3]);
        if (p) s3s[o] = v; else o3s[o] = v;
    }
    __syncthreads();

    float ce_val = 0.f;
    int o = tid;
    if (tid < 64) {
        float acc = 0.f;
        for (int j = 0; j < 64; ++j) acc += tw1[o * 128 + j] * s3s[j];
        for (int j = 0; j < 64; ++j) acc += tw1[o * 128 + 64 + j] * (s3s[j] - center[j]);
        t1s[o] = leaky(acc);
    }
    __syncthreads();
    if (tid < 64) {
        float acc = 0.f;
        for (int j = 0; j < 64; ++j) acc += tw2[o * 64 + j] * t1s[j];
        float tex = leaky(acc);
        float sim[4];
        #pragma unroll
        for (int k = 0; k < 4; ++k) {
            float d = tex - proto[k * 64 + o];
            float v = d * d;
            #pragma unroll
            for (int off = 32; off; off >>= 1) v += __shfl_xor(v, off);
            sim[k] = v;
        }
        int cat = 0; float best = sim[0];
        #pragma unroll
        for (int k = 1; k < 4; ++k) if (sim[k] > best) { best = sim[k]; cat = k; }
        float sume = 0.f;
        #pragma unroll
        for (int k = 0; k < 4; ++k) sume += expf(sim[k] - best);
        ce_val = logf(sume);
        float acc2 = 0.f;
        for (int j = 0; j < 64; ++j) acc2 += cw1[o * 128 + j] * o3s[j];
        for (int j = 0; j < 64; ++j) acc2 += cw1[o * 128 + 64 + j] * (o3s[j] - proto[cat * 64 + j]);
        c1s[o] = leaky(acc2);
        acc2 = 0.f;
        for (int j = 0; j < 64; ++j) acc2 += qw1[o * 64 + j] * o3s[j];
        q1s[o] = leaky(acc2);
    }
    __syncthreads();
    if (tid < 64) {
        float acc = 0.f;
        for (int j = 0; j < 64; ++j) acc += cw2[o * 64 + j] * c1s[j];
        float cf = leaky(acc);
        float dc = cf - center[o];
        float cs = dc * dc;
        #pragma unroll
        for (int off = 32; off; off >>= 1) cs += __shfl_xor(cs, off);
        acc = 0.f;
        for (int j = 0; j < 64; ++j) acc += qw2[o * 64 + j] * q1s[j];
        float qf = leaky(acc);
        float dq = qf - center[o];
        float os = dq * dq;
        #pragma unroll
        for (int off = 32; off; off >>= 1) os += __shfl_xor(os, off);
        if (o == 0) {
            __hip_atomic_store(&ce_t[b], ce_val, __ATOMIC_RELAXED, __HIP_MEMORY_SCOPE_AGENT);
            __hip_atomic_store(&osv[b],  os,     __ATOMIC_RELAXED, __HIP_MEMORY_SCOPE_AGENT);
            __hip_atomic_store(&csv[b],  cs,     __ATOMIC_RELAXED, __HIP_MEMORY_SCOPE_AGENT);
            __hip_atomic_store(&alv[b],  fabsf(os - cs), __ATOMIC_RELAXED, __HIP_MEMORY_SCOPE_AGENT);
        }
    }
    __syncthreads();
    if (tid == 0) {
        asm volatile("s_waitcnt vmcnt(0)" ::: "memory");
        int old = __hip_atomic_fetch_add(&cnt[3], 1, __ATOMIC_RELAXED, __HIP_MEMORY_SCOPE_AGENT);
        flag = (old == 127);
    }
    __syncthreads();
    if (flag) {
        float v0 = 0.f, v1 = 0.f, v2 = 0.f, v3 = 0.f;
        if (tid < 128) {    // relaxed atomic loads bypass L2 -> read LLC directly
            v0 = __hip_atomic_load(&ce_t[tid], __ATOMIC_RELAXED, __HIP_MEMORY_SCOPE_AGENT);
            v1 = __hip_atomic_load(&osv[tid],  __ATOMIC_RELAXED, __HIP_MEMORY_SCOPE_AGENT);
            v2 = __hip_atomic_load(&csv[tid],  __ATOMIC_RELAXED, __HIP_MEMORY_SCOPE_AGENT);
            v3 = __hip_atomic_load(&alv[tid],  __ATOMIC_RELAXED, __HIP_MEMORY_SCOPE_AGENT);
        }
        float v[4] = { v0, v1, v2, v3 };
        int lane = tid & 63, wv = tid >> 6;
        #pragma unroll
        for (int i = 0; i < 4; ++i) {
            float x = v[i];
            #pragma unroll
            for (int off = 32; off; off >>= 1) x += __shfl_xor(x, off);
            if (lane == 0) tmp[i][wv] = x;
        }
        __syncthreads();
        if (tid < 4) {
            float s = 0.f;
            #pragma unroll
            for (int j = 0; j < 8; ++j) s += tmp[tid][j];
            out[tid] = s * (1.0f / 128.0f);
        }
    }
}

// ---------- launcher ----------
extern "C" void kernel_launch(void* const* d_in, const int* in_sizes, int n_in,
                              void* d_out, int out_size, void* d_ws, size_t ws_size,
                              hipStream_t stream)
{
    const float* x_mid     = (const float*)d_in[0];
    const float* x_deep    = (const float*)d_in[1];
    const float* w_shallow = (const float*)d_in[2];
    const float* ow1 = (const float*)d_in[3];
    const float* ow2 = (const float*)d_in[4];
    const float* ow3 = (const float*)d_in[5];
    const float* sw1 = (const float*)d_in[6];
    const float* sw2 = (const float*)d_in[7];
    const float* sw3 = (const float*)d_in[8];
    const float* tw1 = (const float*)d_in[9];
    const float* tw2 = (const float*)d_in[10];
    const float* cw1 = (const float*)d_in[11];
    const float* cw2 = (const float*)d_in[12];
    const float* qw1 = (const float*)d_in[13];
    const float* qw2 = (const float*)d_in[14];
    const float* center = (const float*)d_in[15];
    const float* proto  = (const float*)d_in[16];
    float* out = (float*)d_out;

    float* wf = (float*)d_ws;
    unsigned short* xm_b = (unsigned short*)(wf + 656384);            // [128,512]
    unsigned short* xd_b = (unsigned short*)((char*)xm_b + 131072);   // [128,2048]

    // dispatch 1: means + zero C bufs/counters (641 zero blocks)
    means_kernel<<<33409, 256, 0, stream>>>(x_mid, x_deep, xm_b, xd_b, (float4*)wf);

    // dispatch 2: everything else (relaxed-spin gated phases)
    fused_kernel<<<1152, 512, 0, stream>>>(wf, xm_b, xd_b, w_shallow,
                                           ow1, ow2, ow3, sw1, sw2, sw3,
                                           tw1, tw2, cw1, cw2, qw1, qw2,
                                           center, proto, out);
}

// Round 9
// 99.935 us; speedup vs baseline: 1.8376x; 1.3307x over previous
//
#include <hip/hip_runtime.h>
#include <hip/hip_bf16.h>
#include <math.h>

typedef __attribute__((ext_vector_type(8))) short bf16x8;
typedef __attribute__((ext_vector_type(4))) float f32x4;
typedef __attribute__((ext_vector_type(4))) unsigned short u16x4;

__device__ __forceinline__ float leaky(float x) { return x > 0.0f ? x : 0.01f * x; }

__device__ __forceinline__ unsigned short f2b(float f) {
    unsigned u = __builtin_bit_cast(unsigned, f);
    u += 0x7fffu + ((u >> 16) & 1u);
    return (unsigned short)(u >> 16);
}

__device__ __forceinline__ bf16x8 cvt8(float4 u0, float4 u1) {
    bf16x8 r;
    r[0] = (short)f2b(u0.x); r[1] = (short)f2b(u0.y);
    r[2] = (short)f2b(u0.z); r[3] = (short)f2b(u0.w);
    r[4] = (short)f2b(u1.x); r[5] = (short)f2b(u1.y);
    r[6] = (short)f2b(u1.z); r[7] = (short)f2b(u1.w);
    return r;
}

// ================= D1: Wfuse GEMM + both HW means + zero of atomic-C region =================
// bids [0,256):        Ws1[1024,512] = sw1[1024,2048] @ w_shallow[2048,512]  (bf16 out)
// bids [256,16640):    x_mid  [128,512,28,28]  -> xm_b (mean over HW, bf16)
// bids [16640,33024):  x_deep [128,2048,7,7]   -> xd_b
// bids [33024,33409):  zero wf[0..394240) floats (C2o,C2s,C3o,C3s,cnt,scalars)
__global__ __launch_bounds__(256) void prep_kernel(
    const float* __restrict__ xm, const float* __restrict__ xd,
    const float* __restrict__ sw1, const float* __restrict__ wsh,
    unsigned short* __restrict__ Ws1,
    unsigned short* __restrict__ xm_b, unsigned short* __restrict__ xd_b,
    float4* __restrict__ zbase)
{
    const int blk = blockIdx.x;
    const int tid = threadIdx.x;

    if (blk < 256) {
        // ---- Wfuse: 4 waves, M-tile 64, N-tile 32, full K=2048 ----
        const int l = tid & 63, lr = l & 15, lc = l >> 4, w = tid >> 6;
        const int m0 = (blk >> 4) * 64 + w * 16;       // 16 m-tiles of 64
        const int n0 = (blk & 15) * 32;                // 16 n-tiles of 32
        const float* ap = sw1 + (size_t)(m0 + lr) * 2048 + lc * 8;
        f32x4 acc0 = {0.f,0.f,0.f,0.f}, acc1 = {0.f,0.f,0.f,0.f};
        for (int kt = 0; kt < 2048; kt += 32) {
            bf16x8 a = cvt8(*(const float4*)(ap + kt), *(const float4*)(ap + kt + 4));
            bf16x8 b0, b1;
            #pragma unroll
            for (int j = 0; j < 8; ++j) {
                int kk = kt + lc * 8 + j;
                b0[j] = (short)f2b(wsh[(size_t)kk * 512 + n0 + lr]);
                b1[j] = (short)f2b(wsh[(size_t)kk * 512 + n0 + 16 + lr]);
            }
            acc0 = __builtin_amdgcn_mfma_f32_16x16x32_bf16(a, b0, acc0, 0, 0, 0);
            acc1 = __builtin_amdgcn_mfma_f32_16x16x32_bf16(a, b1, acc1, 0, 0, 0);
        }
        #pragma unroll
        for (int r = 0; r < 4; ++r) {
            int m = m0 + lc * 4 + r;
            Ws1[(size_t)m * 512 + n0 + lr]      = f2b(acc0[r]);
            Ws1[(size_t)m * 512 + n0 + 16 + lr] = f2b(acc1[r]);
        }
        return;
    }
    if (blk < 16640) {
        int b2 = blk - 256;
        int lane = tid & 63, wid = tid >> 6;
        int row  = b2 * 4 + wid;                       // 0..65535
        const float4* r = (const float4*)(xm + (size_t)row * 784);
        float s = 0.0f;
        for (int i = lane; i < 196; i += 64) {
            float4 v = r[i];
            s += v.x + v.y + v.z + v.w;
        }
        #pragma unroll
        for (int off = 32; off; off >>= 1) s += __shfl_xor(s, off);
        if (lane == 0) xm_b[row] = f2b(s * (1.0f / 784.0f));
        return;
    }
    if (blk < 33024) {
        int b3 = blk - 16640;
        int sub = tid & 15, rr = tid >> 4;
        int row = b3 * 16 + rr;                        // 0..262143
        const float* base = xd + (size_t)row * 49;
        float s = base[sub] + base[sub + 16] + base[sub + 32];
        if (sub == 0) s += base[48];
        #pragma unroll
        for (int off = 8; off; off >>= 1) s += __shfl_xor(s, off);
        if (sub == 0) xd_b[row] = f2b(s * (1.0f / 49.0f));
        return;
    }
    {   // zero region
        int idx = (blk - 33024) * 256 + tid;           // 385*256 = 98560 float4
        zbase[idx] = make_float4(0.f, 0.f, 0.f, 0.f);
    }
}

// ================= shared GEMM phase (R6-validated) =================
// C[m][n] += actA(A[m][k-slice]) @ B[n][k-slice]^T, atomic fp32 C.
// block 512 thr = 8 waves; wave w rows 16w..16w+15, cols n0..n0+31; LDS-staged bf16 B.
// A lane layout: row=l&15, kchunk=(l>>4)*8 ; C/D: col=l&15, row=(l>>4)*4+reg
__device__ __forceinline__ void gemm_phase(
    const void* __restrict__ A, int af, int aact,
    const void* __restrict__ B, int bfB,
    float* __restrict__ C,
    int N, int K, int Kc, int k0, int n0,
    unsigned short (*Bs)[72], int tid)
{
    const int l  = tid & 63;
    const int lr = l & 15;
    const int lc = l >> 4;
    const int m0 = (tid >> 6) * 16;
    const int srow = tid >> 4;                     // 0..31
    const int scol = (tid & 15) * 4;               // 0,4,..,60

    f32x4 acc0 = {0.f,0.f,0.f,0.f}, acc1 = {0.f,0.f,0.f,0.f};

    for (int kt = 0; kt < Kc; kt += 64) {
        if (!bfB) {
            float4 v = *(const float4*)((const float*)B + (size_t)(n0 + srow) * K + k0 + kt + scol);
            __syncthreads();
            Bs[srow][scol + 0] = f2b(v.x);
            Bs[srow][scol + 1] = f2b(v.y);
            Bs[srow][scol + 2] = f2b(v.z);
            Bs[srow][scol + 3] = f2b(v.w);
        } else {
            u16x4 v = *(const u16x4*)((const unsigned short*)B + (size_t)(n0 + srow) * K + k0 + kt + scol);
            __syncthreads();
            Bs[srow][scol + 0] = v.x;
            Bs[srow][scol + 1] = v.y;
            Bs[srow][scol + 2] = v.z;
            Bs[srow][scol + 3] = v.w;
        }
        __syncthreads();

        #pragma unroll
        for (int kc = 0; kc < 2; ++kc) {
            size_t aoff = (size_t)(m0 + lr) * K + k0 + kt + kc * 32 + lc * 8;
            bf16x8 a;
            if (!af) {
                a = *(const bf16x8*)((const unsigned short*)A + aoff);
            } else {
                const float* p = (const float*)A + aoff;
                float4 u0 = *(const float4*)p;
                float4 u1 = *(const float4*)(p + 4);
                if (aact) {
                    u0.x = leaky(u0.x); u0.y = leaky(u0.y);
                    u0.z = leaky(u0.z); u0.w = leaky(u0.w);
                    u1.x = leaky(u1.x); u1.y = leaky(u1.y);
                    u1.z = leaky(u1.z); u1.w = leaky(u1.w);
                }
                a = cvt8(u0, u1);
            }
            bf16x8 b0 = *(const bf16x8*)&Bs[lr][kc * 32 + lc * 8];
            bf16x8 b1 = *(const bf16x8*)&Bs[16 + lr][kc * 32 + lc * 8];
            acc0 = __builtin_amdgcn_mfma_f32_16x16x32_bf16(a, b0, acc0, 0, 0, 0);
            acc1 = __builtin_amdgcn_mfma_f32_16x16x32_bf16(a, b1, acc1, 0, 0, 0);
        }
    }

    #pragma unroll
    for (int r = 0; r < 4; ++r) {
        int m = m0 + lc * 4 + r;
        atomicAdd(&C[(size_t)m * N + n0 + lr],      acc0[r]);
        atomicAdd(&C[(size_t)m * N + n0 + 16 + lr], acc1[r]);
    }
}

// ================= D2: both layer-1 GEMMs =================
// bids [0,256):   C2o += xd_b @ ow1^T   (N=1024, K=2048, S=8)
// bids [256,384): C2s += xm_b @ Ws1^T   (N=1024, K=512,  S=4)  [Ws1 bf16]
__global__ __launch_bounds__(512) void l1_kernel(
    const unsigned short* __restrict__ xd_b, const unsigned short* __restrict__ xm_b,
    const float* __restrict__ ow1, const unsigned short* __restrict__ Ws1,
    float* __restrict__ C2o, float* __restrict__ C2s)
{
    __shared__ unsigned short Bs[32][72];
    const int bid = blockIdx.x, tid = threadIdx.x;
    if (bid < 256) {
        int nt = bid >> 3, s = bid & 7;
        gemm_phase(xd_b, 0, 0, ow1, 0, C2o, 1024, 2048, 256, s * 256, nt * 32, Bs, tid);
    } else {
        int idx = bid - 256, nt = idx >> 2, s = idx & 3;
        gemm_phase(xm_b, 0, 0, Ws1, 1, C2s, 1024, 512, 128, s * 128, nt * 32, Bs, tid);
    }
}

// ================= D3: both layer-2 GEMMs =================
// z=0: C3o += leaky(C2o) @ ow2^T ; z=1: C3s += leaky(C2s) @ sw2^T  (N=512, K=1024, S=8)
__global__ __launch_bounds__(512) void l2_kernel(
    const float* __restrict__ C2o, const float* __restrict__ C2s,
    const float* __restrict__ ow2, const float* __restrict__ sw2,
    float* __restrict__ C3o, float* __restrict__ C3s)
{
    __shared__ unsigned short Bs[32][72];
    const int bid = blockIdx.x, tid = threadIdx.x;
    const int z = bid >> 7, idx = bid & 127;
    const int nt = idx >> 3, s = idx & 7;
    gemm_phase(z ? (const void*)C2s : (const void*)C2o, 1, 1,
               z ? (const void*)sw2 : (const void*)ow2, 0,
               z ? C3s : C3o, 512, 1024, 128, s * 128, nt * 32, Bs, tid);
}

// ================= D4: tail (per-sample) + last-block finalize =================
__global__ __launch_bounds__(256) void tail_kernel(
    const float* __restrict__ C3o, const float* __restrict__ C3s,
    const float* __restrict__ ow3, const float* __restrict__ sw3,
    const float* __restrict__ tw1, const float* __restrict__ tw2,
    const float* __restrict__ cw1, const float* __restrict__ cw2,
    const float* __restrict__ qw1, const float* __restrict__ qw2,
    const float* __restrict__ center, const float* __restrict__ proto,
    int* __restrict__ cnt, float* __restrict__ ce_t, float* __restrict__ osv,
    float* __restrict__ csv, float* __restrict__ alv,
    float* __restrict__ out)
{
    const int b = blockIdx.x;
    const int tid = threadIdx.x;
    __shared__ float o2r[512], s2r[512];
    __shared__ float red[2][64][4];
    __shared__ float o3s[64], s3s[64], t1s[64], c1s[64], q1s[64];
    __shared__ float tmp[4][4];
    __shared__ int flag;

    for (int e = tid; e < 512; e += 256) {
        o2r[e] = leaky(C3o[b * 512 + e]);
        s2r[e] = leaky(C3s[b * 512 + e]);
    }
    __syncthreads();
    {   // both layer-3 matvecs: o = output idx, q = K-quarter; path interleaved
        int o = (tid >> 2) & 63, q = tid & 3, p = tid >> 8;   // p always 0 at 256 thr
        (void)p;
        const float* wro = ow3 + (size_t)o * 512 + q * 128;
        const float* wrs = sw3 + (size_t)o * 512 + q * 128;
        const float* xo = o2r + q * 128;
        const float* xs = s2r + q * 128;
        float ao = 0.f, as_ = 0.f;
        for (int j = 0; j < 128; ++j) {
            ao  += wro[j] * xo[j];
            as_ += wrs[j] * xs[j];
        }
        red[0][o][q] = ao;
        red[1][o][q] = as_;
    }
    __syncthreads();
    if (tid < 128) {
        int p = tid >> 6, o = tid & 63;
        float v = leaky(red[p][o][0] + red[p][o][1] + red[p][o][2] + red[p][o][3]);
        if (p) s3s[o] = v; else o3s[o] = v;
    }
    __syncthreads();

    float ce_val = 0.f;
    int o = tid;
    if (tid < 64) {
        float acc = 0.f;
        for (int j = 0; j < 64; ++j) acc += tw1[o * 128 + j] * s3s[j];
        for (int j = 0; j < 64; ++j) acc += tw1[o * 128 + 64 + j] * (s3s[j] - center[j]);
        t1s[o] = leaky(acc);
    }
    __syncthreads();
    if (tid < 64) {
        float acc = 0.f;
        for (int j = 0; j < 64; ++j) acc += tw2[o * 64 + j] * t1s[j];
        float tex = leaky(acc);
        float sim[4];
        #pragma unroll
        for (int k = 0; k < 4; ++k) {
            float d = tex - proto[k * 64 + o];
            float v = d * d;
            #pragma unroll
            for (int off = 32; off; off >>= 1) v += __shfl_xor(v, off);
            sim[k] = v;
        }
        int cat = 0; float best = sim[0];
        #pragma unroll
        for (int k = 1; k < 4; ++k) if (sim[k] > best) { best = sim[k]; cat = k; }
        float sume = 0.f;
        #pragma unroll
        for (int k = 0; k < 4; ++k) sume += expf(sim[k] - best);
        ce_val = logf(sume);
        float acc2 = 0.f;
        for (int j = 0; j < 64; ++j) acc2 += cw1[o * 128 + j] * o3s[j];
        for (int j = 0; j < 64; ++j) acc2 += cw1[o * 128 + 64 + j] * (o3s[j] - proto[cat * 64 + j]);
        c1s[o] = leaky(acc2);
        acc2 = 0.f;
        for (int j = 0; j < 64; ++j) acc2 += qw1[o * 64 + j] * o3s[j];
        q1s[o] = leaky(acc2);
    }
    __syncthreads();
    if (tid < 64) {
        float acc = 0.f;
        for (int j = 0; j < 64; ++j) acc += cw2[o * 64 + j] * c1s[j];
        float cf = leaky(acc);
        float dc = cf - center[o];
        float cs = dc * dc;
        #pragma unroll
        for (int off = 32; off; off >>= 1) cs += __shfl_xor(cs, off);
        acc = 0.f;
        for (int j = 0; j < 64; ++j) acc += qw2[o * 64 + j] * q1s[j];
        float qf = leaky(acc);
        float dq = qf - center[o];
        float os = dq * dq;
        #pragma unroll
        for (int off = 32; off; off >>= 1) os += __shfl_xor(os, off);
        if (o == 0) {
            __hip_atomic_store(&ce_t[b], ce_val, __ATOMIC_RELAXED, __HIP_MEMORY_SCOPE_AGENT);
            __hip_atomic_store(&osv[b],  os,     __ATOMIC_RELAXED, __HIP_MEMORY_SCOPE_AGENT);
            __hip_atomic_store(&csv[b],  cs,     __ATOMIC_RELAXED, __HIP_MEMORY_SCOPE_AGENT);
            __hip_atomic_store(&alv[b],  fabsf(os - cs), __ATOMIC_RELAXED, __HIP_MEMORY_SCOPE_AGENT);
        }
    }
    __syncthreads();
    if (tid == 0) {
        asm volatile("s_waitcnt vmcnt(0)" ::: "memory");
        int old = __hip_atomic_fetch_add(cnt, 1, __ATOMIC_ACQ_REL, __HIP_MEMORY_SCOPE_AGENT);
        flag = (old == 127);
    }
    __syncthreads();
    if (flag) {
        float v0 = 0.f, v1 = 0.f, v2 = 0.f, v3 = 0.f;
        if (tid < 128) {
            v0 = __hip_atomic_load(&ce_t[tid], __ATOMIC_RELAXED, __HIP_MEMORY_SCOPE_AGENT);
            v1 = __hip_atomic_load(&osv[tid],  __ATOMIC_RELAXED, __HIP_MEMORY_SCOPE_AGENT);
            v2 = __hip_atomic_load(&csv[tid],  __ATOMIC_RELAXED, __HIP_MEMORY_SCOPE_AGENT);
            v3 = __hip_atomic_load(&alv[tid],  __ATOMIC_RELAXED, __HIP_MEMORY_SCOPE_AGENT);
        }
        float v[4] = { v0, v1, v2, v3 };
        int lane = tid & 63, wv = tid >> 6;
        #pragma unroll
        for (int i = 0; i < 4; ++i) {
            float x = v[i];
            #pragma unroll
            for (int off = 32; off; off >>= 1) x += __shfl_xor(x, off);
            if (lane == 0) tmp[i][wv] = x;
        }
        __syncthreads();
        if (tid < 4) {
            float s = 0.f;
            #pragma unroll
            for (int j = 0; j < 4; ++j) s += tmp[tid][j];
            out[tid] = s * (1.0f / 128.0f);
        }
    }
}

// ================= launcher =================
extern "C" void kernel_launch(void* const* d_in, const int* in_sizes, int n_in,
                              void* d_out, int out_size, void* d_ws, size_t ws_size,
                              hipStream_t stream)
{
    const float* x_mid     = (const float*)d_in[0];
    const float* x_deep    = (const float*)d_in[1];
    const float* w_shallow = (const float*)d_in[2];
    const float* ow1 = (const float*)d_in[3];
    const float* ow2 = (const float*)d_in[4];
    const float* ow3 = (const float*)d_in[5];
    const float* sw1 = (const float*)d_in[6];
    const float* sw2 = (const float*)d_in[7];
    const float* sw3 = (const float*)d_in[8];
    const float* tw1 = (const float*)d_in[9];
    const float* tw2 = (const float*)d_in[10];
    const float* cw1 = (const float*)d_in[11];
    const float* cw2 = (const float*)d_in[12];
    const float* qw1 = (const float*)d_in[13];
    const float* qw2 = (const float*)d_in[14];
    const float* center = (const float*)d_in[15];
    const float* proto  = (const float*)d_in[16];
    float* out = (float*)d_out;

    float* wf = (float*)d_ws;
    float* C2o = wf;                    // [128,1024] = 131072
    float* C2s = wf + 131072;           // [128,1024]
    float* C3o = wf + 262144;           // [128,512]  = 65536
    float* C3s = wf + 327680;           // [128,512]
    int*   cnt = (int*)(wf + 393216);   // [4]
    float* ce_t = wf + 393472;          // [128] x4  (inside zero region, rewritten every call)
    float* osv  = ce_t + 128;
    float* csv  = ce_t + 256;
    float* alv  = ce_t + 384;
    // zero region covers wf[0 .. 394240)
    unsigned short* Ws1  = (unsigned short*)(wf + 394240);      // [1024,512] bf16
    unsigned short* xm_b = Ws1 + 524288;                        // [128,512]
    unsigned short* xd_b = xm_b + 65536;                        // [128,2048]

    // D1: Wfuse (256) + mid means (16384) + deep means (16384) + zero (385)
    prep_kernel<<<33409, 256, 0, stream>>>(x_mid, x_deep, sw1, w_shallow,
                                           Ws1, xm_b, xd_b, (float4*)wf);

    // D2: both layer-1 GEMMs (384 blocks)
    l1_kernel<<<384, 512, 0, stream>>>(xd_b, xm_b, ow1, Ws1, C2o, C2s);

    // D3: both layer-2 GEMMs (256 blocks)
    l2_kernel<<<256, 512, 0, stream>>>(C2o, C2s, ow2, sw2, C3o, C3s);

    // D4: tail + finalize (128 blocks)
    tail_kernel<<<128, 256, 0, stream>>>(C3o, C3s, ow3, sw3, tw1, tw2, cw1, cw2,
                                         qw1, qw2, center, proto,
                                         cnt, ce_t, osv, csv, alv, out);
}